// Round 6
// baseline (762.049 us; speedup 1.0000x reference)
//
#include <hip/hip_runtime.h>
#include <cstdint>

// ---------------------------------------------------------------------------
// NVFP4 fake-quant GEMM: out = fq4(x) @ fq4(w)^T + bias
// fq4: per-16-group (along K) scale = e4m3_rt(amax/6), values on e2m1 grid.
// dq = q*scale is EXACT in bf16 -> quantize to bf16 in d_ws, bf16-MFMA GEMM.
//
// GEMM v5.1 ("overlap", pinned): 256x256, BK=64, 8 waves, 16x16x32 MFMA.
// Cycle model (r1 counters): MFMA 2064 cyc/tile, LDS-read ~1536+512 cyc/tile;
// lockstep serialized them (5100 cyc/tile, MfmaUtil 43%). Here each quadrant's
// ds_reads are issued INSIDE the previous quadrant's MFMA window with no
// waitcnt until next use (compiler emits counted lgkmcnt) -> LDS service
// overlaps MFMA. 4 barriers/tile, 2 counted vmcnt/tile (8 @ph0, 6 @pre-ph3).
// v5.1 adds sched_barrier(0) pins at every boundary (rule #18: hipcc moves
// ops across inline-asm waits) and launch_bounds(512,1) (no forced spills;
// LDS=128KiB already caps at 1 block/CU).
// ---------------------------------------------------------------------------

typedef __attribute__((ext_vector_type(8))) __bf16 bf16x8;
typedef __attribute__((ext_vector_type(4))) float f32x4;

typedef __attribute__((address_space(1))) void gvoid;
typedef __attribute__((address_space(3))) void lvoid;

__device__ __forceinline__ float fp8_e4m3_rt(float x) {
    if (x < 0.015625f) {
        return __builtin_rintf(x * 512.0f) * (1.0f / 512.0f);
    }
    unsigned u = __float_as_uint(x);
    unsigned lsb = (u >> 20) & 1u;
    u = (u + 0x7FFFFu + lsb) & ~0xFFFFFu;
    return __uint_as_float(u);
}

// Divide-free e2m1 bucket of fl32(|v|/scale) (exactness proved; absmax=0).
__device__ __forceinline__ uint2 quant_quad(float4 v) {
    float ax = fabsf(v.x), ay = fabsf(v.y), az = fabsf(v.z), aw = fabsf(v.w);
    float a = fmaxf(fmaxf(ax, ay), fmaxf(az, aw));
    a = fmaxf(a, __shfl_xor(a, 1));
    a = fmaxf(a, __shfl_xor(a, 2));
    float scale = fp8_e4m3_rt(a / 6.0f);
    float sN = -scale;
    float n0 = sN * 0x1p-27f;
    float n1 = sN * 0x1p-25f;
    float n2 = sN * 0x1p-24f;
    float n4 = sN * 0x1p-23f;
    float n6 = sN * 0x1p-22f;
    float e[4] = {v.x, v.y, v.z, v.w};
    unsigned r[4];
    #pragma unroll
    for (int i = 0; i < 4; ++i) {
        float av = fabsf(e[i]);
        float q =
            fmaf(sN, 0.25f, av) < n0 ? 0.0f :
            fmaf(sN, 0.75f, av) < n1 ? 0.5f :
            fmaf(sN, 1.25f, av) < n2 ? 1.0f :
            fmaf(sN, 1.75f, av) < n2 ? 1.5f :
            fmaf(sN, 2.5f,  av) < n4 ? 2.0f :
            fmaf(sN, 3.5f,  av) < n4 ? 3.0f :
            fmaf(sN, 5.0f,  av) < n6 ? 4.0f : 6.0f;
        float dq = q * scale;
        r[i] = (__float_as_uint(dq) | (__float_as_uint(e[i]) & 0x80000000u)) >> 16;
    }
    uint2 o;
    o.x = r[0] | (r[1] << 16);
    o.y = r[2] | (r[3] << 16);
    return o;
}

__global__ __launch_bounds__(256)
void quant_fp4_fused(const float* __restrict__ x, const float* __restrict__ w,
                     uint16_t* __restrict__ out, int xquads, int totquads) {
    const int half = totquads >> 1;
    const int t0 = blockIdx.x * 256 + threadIdx.x;
    uint2* o2 = (uint2*)out;
    if (t0 < half) {
        const float4* s0 = (t0 < xquads) ? ((const float4*)x) + t0
                                         : ((const float4*)w) + (t0 - xquads);
        o2[t0] = quant_quad(*s0);
    }
    const int q1 = t0 + half;
    if (q1 < totquads) {
        const float4* s1 = (q1 < xquads) ? ((const float4*)x) + q1
                                         : ((const float4*)w) + (q1 - xquads);
        o2[q1] = quant_quad(*s1);
    }
}

// ---------------------------------------------------------------------------
// GEMM. LDS: lds[2][2][256*64] bf16 = 128 KiB; (row,k) at row*64+(k^((row&7)<<3)).
// A rows natural; B rows natural (row = wn*64 + nh*32 + fj*16 + l15).
// Chunk ch covers rows [ch*64, ch*64+64). Per-tile issue order:
//   ph1: A ch{0,2}(t+2); ph2: B ch{0,1}(t+2); ph3: B ch{2,3}, A ch{1,3}(t+2).
// Per-tile schedule (single barrier per boundary; quadrant (mh,nh)):
//   vmcnt(8) bar | ph0: rd b1[t]       ; MFMA(0,0) a0,b0
//            bar | ph1: rd a1[t]       ; stage A{0,2}[t+2] ; MFMA(0,1) a0,b1
//            bar | ph2:                  stage B{0,1}[t+2] ; MFMA(1,1) a1,b1
//   vmcnt(6) bar | ph3: rd a0',b0'[t+1]; stage B{2,3},A{1,3}[t+2]; MFMA(1,0)
// Ledger (invariant: 10 outstanding at ph0 = [A1,A3(t)] + [8 x (t+1)]):
//   vmcnt(8) retires A1,A3(t) -> ALL of tile t in LDS at ph0.
//   pre-ph3 vmcnt(6) retires A{0,2},B{0..3}(t+1) -> ph3's a0'/b0' reads safe.
// WAR: every region staged >= 1 barrier after its readers' MFMA-forced
// lgkm service (verified region-by-region). Tails: (8,2) then (0,0).
// ---------------------------------------------------------------------------
#define BK 64
#define THREADS 512

#define SB __builtin_amdgcn_sched_barrier(0)
#define VMW(S) do { asm volatile("s_waitcnt vmcnt(" S ")" ::: "memory"); SB; } while (0)
#define PHB do { SB; asm volatile("" ::: "memory");                           \
    __builtin_amdgcn_s_barrier();                                             \
    asm volatile("" ::: "memory"); SB; } while (0)

#define LDA(dst, B_, mh) do { _Pragma("unroll")                               \
    for (int fi_ = 0; fi_ < 4; ++fi_) {                                       \
        dst[fi_][0] = *(const bf16x8*)&lds[B_][0][aBase + (mh)*4096 + fi_*1024 + kx0]; \
        dst[fi_][1] = *(const bf16x8*)&lds[B_][0][aBase + (mh)*4096 + fi_*1024 + kx1]; \
    } } while (0)

#define LDB(dst, B_, nh) do { _Pragma("unroll")                               \
    for (int fj_ = 0; fj_ < 2; ++fj_) {                                       \
        dst[fj_][0] = *(const bf16x8*)&lds[B_][1][bBase + (nh)*2048 + fj_*1024 + kx0]; \
        dst[fj_][1] = *(const bf16x8*)&lds[B_][1][bBase + (nh)*2048 + fj_*1024 + kx1]; \
    } } while (0)

#define STGA(B_, ch, ko) __builtin_amdgcn_global_load_lds(                    \
    (gvoid*)(pA + (size_t)off[ch] + kAdv + (ko)),                             \
    (lvoid*)&lds[B_][0][(ch)*4096 + ldsU], 16, 0, 0)
#define STGB(B_, ch, ko) __builtin_amdgcn_global_load_lds(                    \
    (gvoid*)(pB + (size_t)off[ch] + kAdv + (ko)),                             \
    (lvoid*)&lds[B_][1][(ch)*4096 + ldsU], 16, 0, 0)

#define QUAD(A_, Bf_, mh, nh) do {                                            \
    __builtin_amdgcn_s_setprio(1);                                            \
    _Pragma("unroll") for (int fi_ = 0; fi_ < 4; ++fi_)                       \
    _Pragma("unroll") for (int fj_ = 0; fj_ < 2; ++fj_) {                     \
        f32x4 c_ = acc[(mh)*4 + fi_][(nh)*2 + fj_];                           \
        c_ = __builtin_amdgcn_mfma_f32_16x16x32_bf16(A_[fi_][0], Bf_[fj_][0], c_, 0, 0, 0); \
        c_ = __builtin_amdgcn_mfma_f32_16x16x32_bf16(A_[fi_][1], Bf_[fj_][1], c_, 0, 0, 0); \
        acc[(mh)*4 + fi_][(nh)*2 + fj_] = c_;                                 \
    }                                                                         \
    __builtin_amdgcn_s_setprio(0); } while (0)

// One K-tile. AC/BC: this tile's a0/b0 (already in regs). AN/BN: filled in
// ph3 with next tile's a0/b0 from buffer B_^1.
#define KTILE(B_, STG_, AHD_, SK_, W0S, W3S, AC, BC, AN, BN) do {             \
    VMW(W0S);                                                                 \
    PHB;                                                                      \
    /* ph0 */                                                                 \
    LDB(b1, B_, 1);                                                           \
    QUAD(AC, BC, 0, 0);                                                       \
    PHB;                                                                      \
    /* ph1 */                                                                 \
    LDA(a1, B_, 1);                                                           \
    if (STG_) { STGA(B_, 0, SK_); STGA(B_, 2, SK_); }                         \
    QUAD(AC, b1, 0, 1);                                                       \
    PHB;                                                                      \
    /* ph2 */                                                                 \
    if (STG_) { STGB(B_, 0, SK_); STGB(B_, 1, SK_); }                         \
    QUAD(a1, b1, 1, 1);                                                       \
    VMW(W3S);                                                                 \
    PHB;                                                                      \
    /* ph3 */                                                                 \
    if (AHD_) { LDA(AN, (B_) ^ 1, 0); LDB(BN, (B_) ^ 1, 0); }                 \
    if (STG_) { STGB(B_, 2, SK_); STGB(B_, 3, SK_);                           \
                STGA(B_, 1, SK_); STGA(B_, 3, SK_); }                         \
    QUAD(a1, BC, 1, 0);                                                       \
} while (0)

__global__ __launch_bounds__(THREADS, 1)
void gemm_w4a4(const uint16_t* __restrict__ Aq, const uint16_t* __restrict__ Bq,
               const float* __restrict__ bias, float* __restrict__ C,
               int M, int N, int K) {
    __shared__ __align__(16) uint16_t lds[2][2][256 * BK];

    const int tid  = threadIdx.x;
    const int wave = tid >> 6;
    const int lane = tid & 63;
    const int wm   = wave >> 2;            // 0..1  (m half)
    const int wn   = wave & 3;             // 0..3  (n quarter)
    const int l15  = lane & 15;
    const int hi16 = (lane >> 4) << 3;     // 0/8/16/24 (frag k subgroup)
    const int rsw  = (lane & 7) << 3;      // row-swizzle XOR (elems)
    const int kx0  = hi16 ^ rsw;           // k-step 0
    const int kx1  = (32 + hi16) ^ rsw;    // k-step 1
    const int aBase = ((wm << 7) + l15) << 6;   // A frag row * 64
    const int bBase = ((wn << 6) + l15) << 6;   // B frag row * 64
    const int ldsU  = wave << 9;                // wave-uniform stage base

    // ---- bijective XCD swizzle (T1, m204); column-major tile order ----
    const int ntm = M >> 8, nwg = ntm * (N >> 8);
    const int bid = blockIdx.x;
    const int q8 = nwg >> 3, r8 = nwg & 7;
    const int xcd = bid & 7;
    const int wgid = (xcd < r8 ? xcd * (q8 + 1) : r8 * (q8 + 1) + (xcd - r8) * q8)
                     + (bid >> 3);
    const int mBase = (wgid % ntm) << 8;
    const int nBase = (wgid / ntm) << 8;

    // ---- staging source offsets (inverse-swizzled, shared A/B) ----
    // chunk c = i*512 + tid -> linear LDS elems [c*8, c*8+8):
    // row = c>>3, k = ((c&7) ^ (row&7))*8
    uint32_t off[4];
    #pragma unroll
    for (int i = 0; i < 4; ++i) {
        const int c = i * THREADS + tid;
        const int row = c >> 3;
        const int kc = ((c & 7) ^ (row & 7)) << 3;
        off[i] = (uint32_t)row * (uint32_t)K + (uint32_t)kc;
    }
    const uint16_t* pA = Aq + (size_t)mBase * K;
    const uint16_t* pB = Bq + (size_t)nBase * K;

    const int nt = K / BK;   // even, >= 4 (K=4096 -> 64)
    uint32_t kAdv = 0;

    // ---- prologue: stage t0, t1 in canonical order [A02, B0123, A13] ----
    STGA(0, 0, 0); STGA(0, 2, 0); STGB(0, 0, 0); STGB(0, 1, 0);
    STGB(0, 2, 0); STGB(0, 3, 0); STGA(0, 1, 0); STGA(0, 3, 0);
    STGA(1, 0, 64); STGA(1, 2, 64); STGB(1, 0, 64); STGB(1, 1, 64);
    STGB(1, 2, 64); STGB(1, 3, 64); STGA(1, 1, 64); STGA(1, 3, 64);
    VMW("10");                       // t0's A{0,2}, B{0..3} landed
    PHB;

    f32x4 acc[8][4] = {};
    bf16x8 aA[4][2], aB[4][2], bA[2][2], bB[2][2], a1[4][2], b1[2][2];

    // prologue window (plays t-1.ph3): read t0's a0, b0
    LDA(aA, 0, 0);
    LDB(bA, 0, 0);

    kAdv = 2 * BK;   // during pair starting at tk: tile tk+2's k (SK_=0 path)

    for (int tk = 0; tk < nt - 2; tk += 2) {
        KTILE(0, 1, 1, 0,  "8", "6", aA, bA, aB, bB);
        KTILE(1, 1, 1, 64, "8", "6", aB, bB, aA, bA);
        kAdv += 2 * BK;
    }
    // tails: tile nt-2 (no staging), tile nt-1 (no staging, no ahead-reads)
    KTILE(0, 0, 1, 0, "8", "2", aA, bA, aB, bB);
    KTILE(1, 0, 0, 0, "0", "0", aB, bB, aA, bA);

    // ---- epilogue: C/D col = lane&15, row = (lane>>4)*4 + reg ----
    const int rq = (lane >> 4) << 2;
    #pragma unroll
    for (int j = 0; j < 4; ++j) {
        const int col = nBase + (wn << 6) + j * 16 + l15;
        const float bj = bias[col];
        #pragma unroll
        for (int i = 0; i < 8; ++i) {
            const int row0 = mBase + (wm << 7) + i * 16 + rq;
            #pragma unroll
            for (int r = 0; r < 4; ++r)
                C[(size_t)(row0 + r) * N + col] = acc[i][j][r] + bj;
        }
    }
}

extern "C" void kernel_launch(void* const* d_in, const int* in_sizes, int n_in,
                              void* d_out, int out_size, void* d_ws, size_t ws_size,
                              hipStream_t stream) {
    const float* x    = (const float*)d_in[0];
    const float* w    = (const float*)d_in[1];
    const float* bias = (const float*)d_in[2];
    float* out = (float*)d_out;

    const int N = in_sizes[2];
    const int K = in_sizes[1] / N;
    const int M = in_sizes[0] / K;

    uint16_t* xq = (uint16_t*)d_ws;
    uint16_t* wq = xq + (size_t)M * K;

    const int xquads = (M * K) / 4;
    const int totquads = xquads + (N * K) / 4;
    const int half = totquads / 2;
    quant_fp4_fused<<<(half + 255) / 256, 256, 0, stream>>>(x, w, xq, xquads, totquads);

    const int nwg = (M >> 8) * (N >> 8);
    gemm_w4a4<<<nwg, THREADS, 0, stream>>>(xq, wq, bias, out, M, N, K);
}

// Round 7
// 622.266 us; speedup vs baseline: 1.2246x; 1.2246x over previous
//
#include <hip/hip_runtime.h>
#include <cstdint>

// ---------------------------------------------------------------------------
// NVFP4 fake-quant GEMM: out = fq4(x) @ fq4(w)^T + bias
// fq4: per-16-group (along K) scale = e4m3_rt(amax/6), values on e2m1 grid.
// dq = q*scale is EXACT in bf16 -> quantize to bf16 in d_ws, bf16-MFMA GEMM.
//
// GEMM v5.2 ("overlap, no-spill"): 256x256, BK=64, 8 waves, 16x16x32 MFMA.
// v5.1 spilled (WRITE_SIZE 366MB vs C=128MB -> scratch traffic, 525us): the
// cross-tile ahead-read kept 2 full a0/b0 sets live (+96 VGPR). v5.2 reads
// a0/b0 at ph0 of the SAME tile (one ~200cyc exposed LDS burst/tile) and
// pipelines quadrant reads within the tile only:
//   vmcnt(8) bar | ph0: rd a0,b0,b1; lgkm(4);  MFMA(0,0) a0*b0
//                | ph1: rd a1;       lgkm(8);  MFMA(0,1) a0*b1
//            bar | ph2: stage A0,A2,B0,B1[t+2]; lgkm(0); MFMA(1,1) a1*b1
//            bar | ph3: stage B2,B3,A1,A3[t+2];          MFMA(1,0) a1*b0
// 3 barriers + 1 counted vmcnt + 3 counted lgkm per tile. Live frags = 96
// VGPR (a0,a1,b0,b1) + acc in AGPR -> no spill. sched_barrier(0) pins kept
// (rule 18), launch_bounds(512,1) kept (LDS=128KiB caps 1 block/CU anyway).
// WAR ledger: each staged region's readers retire via counted lgkm BEFORE
// the barrier preceding the stage; vmcnt(8) at tile-start retires tile t's
// 8 DMAs (issued during t-2, 5+ phases earlier); t+1's 8 stay in flight.
// ---------------------------------------------------------------------------

typedef __attribute__((ext_vector_type(8))) __bf16 bf16x8;
typedef __attribute__((ext_vector_type(4))) float f32x4;

typedef __attribute__((address_space(1))) void gvoid;
typedef __attribute__((address_space(3))) void lvoid;

__device__ __forceinline__ float fp8_e4m3_rt(float x) {
    if (x < 0.015625f) {
        return __builtin_rintf(x * 512.0f) * (1.0f / 512.0f);
    }
    unsigned u = __float_as_uint(x);
    unsigned lsb = (u >> 20) & 1u;
    u = (u + 0x7FFFFu + lsb) & ~0xFFFFFu;
    return __uint_as_float(u);
}

// Divide-free e2m1 bucket of fl32(|v|/scale) (exactness proved; absmax=0).
__device__ __forceinline__ uint2 quant_quad(float4 v) {
    float ax = fabsf(v.x), ay = fabsf(v.y), az = fabsf(v.z), aw = fabsf(v.w);
    float a = fmaxf(fmaxf(ax, ay), fmaxf(az, aw));
    a = fmaxf(a, __shfl_xor(a, 1));
    a = fmaxf(a, __shfl_xor(a, 2));
    float scale = fp8_e4m3_rt(a / 6.0f);
    float sN = -scale;
    float n0 = sN * 0x1p-27f;
    float n1 = sN * 0x1p-25f;
    float n2 = sN * 0x1p-24f;
    float n4 = sN * 0x1p-23f;
    float n6 = sN * 0x1p-22f;
    float e[4] = {v.x, v.y, v.z, v.w};
    unsigned r[4];
    #pragma unroll
    for (int i = 0; i < 4; ++i) {
        float av = fabsf(e[i]);
        float q =
            fmaf(sN, 0.25f, av) < n0 ? 0.0f :
            fmaf(sN, 0.75f, av) < n1 ? 0.5f :
            fmaf(sN, 1.25f, av) < n2 ? 1.0f :
            fmaf(sN, 1.75f, av) < n2 ? 1.5f :
            fmaf(sN, 2.5f,  av) < n4 ? 2.0f :
            fmaf(sN, 3.5f,  av) < n4 ? 3.0f :
            fmaf(sN, 5.0f,  av) < n6 ? 4.0f : 6.0f;
        float dq = q * scale;
        r[i] = (__float_as_uint(dq) | (__float_as_uint(e[i]) & 0x80000000u)) >> 16;
    }
    uint2 o;
    o.x = r[0] | (r[1] << 16);
    o.y = r[2] | (r[3] << 16);
    return o;
}

__global__ __launch_bounds__(256)
void quant_fp4_fused(const float* __restrict__ x, const float* __restrict__ w,
                     uint16_t* __restrict__ out, int xquads, int totquads) {
    const int half = totquads >> 1;
    const int t0 = blockIdx.x * 256 + threadIdx.x;
    uint2* o2 = (uint2*)out;
    if (t0 < half) {
        const float4* s0 = (t0 < xquads) ? ((const float4*)x) + t0
                                         : ((const float4*)w) + (t0 - xquads);
        o2[t0] = quant_quad(*s0);
    }
    const int q1 = t0 + half;
    if (q1 < totquads) {
        const float4* s1 = (q1 < xquads) ? ((const float4*)x) + q1
                                         : ((const float4*)w) + (q1 - xquads);
        o2[q1] = quant_quad(*s1);
    }
}

// ---------------------------------------------------------------------------
// GEMM. LDS: lds[2][2][256*64] bf16 = 128 KiB; (row,k) at row*64+(k^((row&7)<<3)).
// Chunk ch covers rows [ch*64, ch*64+64). A-half mh0 = chunks {0,2} (rows
// 0-63,128-191 hold frag rows for mh0 since aBase row = wm*128 + i*16 + l15
// spans 0-127/128-255 per wm... A frag rows for mh in {0,1}: wm*128 + mh*64
// ... + i*16 + l15 in [wm*128 + mh*64, wm*128 + mh*64 + 64) -> mh0 = rows
// 0-63 (wm0) and 128-191 (wm1) = chunks {0,2}; mh1 = chunks {1,3}.  B frag
// rows nh*32 + ... span chunks {0,1} for nh0+nh1 of wn 0,1 and {2,3} for
// wn 2,3 -- B's nh split isn't chunk-aligned, but staging order B{0,1} then
// B{2,3} is irrelevant to correctness: ALL B reads (b0,b1) retire in ph0/ph1
// before the ph1-end barrier, so staging any B region in ph2/ph3 is safe.
// ---------------------------------------------------------------------------
#define BK 64
#define THREADS 512

#define SB __builtin_amdgcn_sched_barrier(0)
#define VMW(S) do { asm volatile("s_waitcnt vmcnt(" S ")" ::: "memory"); SB; } while (0)
#define LGKM(S) do { asm volatile("s_waitcnt lgkmcnt(" S ")" ::: "memory"); SB; } while (0)
#define PHB do { SB; asm volatile("" ::: "memory");                           \
    __builtin_amdgcn_s_barrier();                                             \
    asm volatile("" ::: "memory"); SB; } while (0)

#define LDA(dst, B_, mh) do { _Pragma("unroll")                               \
    for (int fi_ = 0; fi_ < 4; ++fi_) {                                       \
        dst[fi_][0] = *(const bf16x8*)&lds[B_][0][aBase + (mh)*4096 + fi_*1024 + kx0]; \
        dst[fi_][1] = *(const bf16x8*)&lds[B_][0][aBase + (mh)*4096 + fi_*1024 + kx1]; \
    } } while (0)

#define LDB(dst, B_, nh) do { _Pragma("unroll")                               \
    for (int fj_ = 0; fj_ < 2; ++fj_) {                                       \
        dst[fj_][0] = *(const bf16x8*)&lds[B_][1][bBase + (nh)*2048 + fj_*1024 + kx0]; \
        dst[fj_][1] = *(const bf16x8*)&lds[B_][1][bBase + (nh)*2048 + fj_*1024 + kx1]; \
    } } while (0)

#define STGA(B_, ch, ko) __builtin_amdgcn_global_load_lds(                    \
    (gvoid*)(pA + (size_t)off[ch] + kAdv + (ko)),                             \
    (lvoid*)&lds[B_][0][(ch)*4096 + ldsU], 16, 0, 0)
#define STGB(B_, ch, ko) __builtin_amdgcn_global_load_lds(                    \
    (gvoid*)(pB + (size_t)off[ch] + kAdv + (ko)),                             \
    (lvoid*)&lds[B_][1][(ch)*4096 + ldsU], 16, 0, 0)

#define QUAD(A_, Bf_, mh, nh) do {                                            \
    __builtin_amdgcn_s_setprio(1);                                            \
    _Pragma("unroll") for (int fi_ = 0; fi_ < 4; ++fi_)                       \
    _Pragma("unroll") for (int fj_ = 0; fj_ < 2; ++fj_) {                     \
        f32x4 c_ = acc[(mh)*4 + fi_][(nh)*2 + fj_];                           \
        c_ = __builtin_amdgcn_mfma_f32_16x16x32_bf16(A_[fi_][0], Bf_[fj_][0], c_, 0, 0, 0); \
        c_ = __builtin_amdgcn_mfma_f32_16x16x32_bf16(A_[fi_][1], Bf_[fj_][1], c_, 0, 0, 0); \
        acc[(mh)*4 + fi_][(nh)*2 + fj_] = c_;                                 \
    }                                                                         \
    __builtin_amdgcn_s_setprio(0); } while (0)

// One K-tile, self-contained (no cross-tile register state).
#define KTILE(B_, STG_, SK_, W0S) do {                                        \
    VMW(W0S);                                                                 \
    PHB;                                                                      \
    /* ph0: issue all of {a0,b0,b1}; wait only a0,b0; MFMA(0,0) */            \
    LDA(a0, B_, 0);                                                           \
    LDB(b0, B_, 0);                                                           \
    LDB(b1, B_, 1);                                                           \
    LGKM("4");                                                                \
    QUAD(a0, b0, 0, 0);                                                       \
    /* ph1: issue a1; wait b1; MFMA(0,1) */                                   \
    LDA(a1, B_, 1);                                                           \
    LGKM("8");                                                                \
    QUAD(a0, b1, 0, 1);                                                       \
    PHB;                                                                      \
    /* ph2: stage first half of t+2; wait a1; MFMA(1,1) */                    \
    if (STG_) { STGA(B_, 0, SK_); STGA(B_, 2, SK_);                           \
                STGB(B_, 0, SK_); STGB(B_, 1, SK_); }                         \
    LGKM("0");                                                                \
    QUAD(a1, b1, 1, 1);                                                       \
    PHB;                                                                      \
    /* ph3: stage second half of t+2; MFMA(1,0) */                            \
    if (STG_) { STGB(B_, 2, SK_); STGB(B_, 3, SK_);                           \
                STGA(B_, 1, SK_); STGA(B_, 3, SK_); }                         \
    QUAD(a1, b0, 1, 0);                                                       \
} while (0)

__global__ __launch_bounds__(THREADS, 1)
void gemm_w4a4(const uint16_t* __restrict__ Aq, const uint16_t* __restrict__ Bq,
               const float* __restrict__ bias, float* __restrict__ C,
               int M, int N, int K) {
    __shared__ __align__(16) uint16_t lds[2][2][256 * BK];

    const int tid  = threadIdx.x;
    const int wave = tid >> 6;
    const int lane = tid & 63;
    const int wm   = wave >> 2;            // 0..1  (m half)
    const int wn   = wave & 3;             // 0..3  (n quarter)
    const int l15  = lane & 15;
    const int hi16 = (lane >> 4) << 3;     // 0/8/16/24 (frag k subgroup)
    const int rsw  = (lane & 7) << 3;      // row-swizzle XOR (elems)
    const int kx0  = hi16 ^ rsw;           // k-step 0
    const int kx1  = (32 + hi16) ^ rsw;    // k-step 1
    const int aBase = ((wm << 7) + l15) << 6;   // A frag row * 64
    const int bBase = ((wn << 6) + l15) << 6;   // B frag row * 64
    const int ldsU  = wave << 9;                // wave-uniform stage base

    // ---- bijective XCD swizzle (T1, m204); column-major tile order ----
    const int ntm = M >> 8, nwg = ntm * (N >> 8);
    const int bid = blockIdx.x;
    const int q8 = nwg >> 3, r8 = nwg & 7;
    const int xcd = bid & 7;
    const int wgid = (xcd < r8 ? xcd * (q8 + 1) : r8 * (q8 + 1) + (xcd - r8) * q8)
                     + (bid >> 3);
    const int mBase = (wgid % ntm) << 8;
    const int nBase = (wgid / ntm) << 8;

    // ---- staging source offsets (inverse-swizzled, shared A/B) ----
    // chunk c = i*512 + tid -> linear LDS elems [c*8, c*8+8):
    // row = c>>3, k = ((c&7) ^ (row&7))*8
    uint32_t off[4];
    #pragma unroll
    for (int i = 0; i < 4; ++i) {
        const int c = i * THREADS + tid;
        const int row = c >> 3;
        const int kc = ((c & 7) ^ (row & 7)) << 3;
        off[i] = (uint32_t)row * (uint32_t)K + (uint32_t)kc;
    }
    const uint16_t* pA = Aq + (size_t)mBase * K;
    const uint16_t* pB = Bq + (size_t)nBase * K;

    const int nt = K / BK;   // even, >= 4 (K=4096 -> 64)
    uint32_t kAdv = 0;

    // ---- prologue: stage t0, t1 in canonical order [A02, B01, B23, A13] ----
    STGA(0, 0, 0); STGA(0, 2, 0); STGB(0, 0, 0); STGB(0, 1, 0);
    STGB(0, 2, 0); STGB(0, 3, 0); STGA(0, 1, 0); STGA(0, 3, 0);
    STGA(1, 0, 64); STGA(1, 2, 64); STGB(1, 0, 64); STGB(1, 1, 64);
    STGB(1, 2, 64); STGB(1, 3, 64); STGA(1, 1, 64); STGA(1, 3, 64);

    f32x4 acc[8][4] = {};
    bf16x8 a0[4][2], a1[4][2], b0[2][2], b1[2][2];

    kAdv = 2 * BK;   // during pair starting at tk: tile tk+2's k (SK_=0 path)

    for (int tk = 0; tk < nt - 2; tk += 2) {
        KTILE(0, 1, 0,  "8");
        KTILE(1, 1, 64, "8");
        kAdv += 2 * BK;
    }
    // tails: tile nt-2 then nt-1, no staging
    KTILE(0, 0, 0, "8");
    KTILE(1, 0, 0, "0");

    // ---- epilogue: C/D col = lane&15, row = (lane>>4)*4 + reg ----
    const int rq = (lane >> 4) << 2;
    #pragma unroll
    for (int j = 0; j < 4; ++j) {
        const int col = nBase + (wn << 6) + j * 16 + l15;
        const float bj = bias[col];
        #pragma unroll
        for (int i = 0; i < 8; ++i) {
            const int row0 = mBase + (wm << 7) + i * 16 + rq;
            #pragma unroll
            for (int r = 0; r < 4; ++r)
                C[(size_t)(row0 + r) * N + col] = acc[i][j][r] + bj;
        }
    }
}

extern "C" void kernel_launch(void* const* d_in, const int* in_sizes, int n_in,
                              void* d_out, int out_size, void* d_ws, size_t ws_size,
                              hipStream_t stream) {
    const float* x    = (const float*)d_in[0];
    const float* w    = (const float*)d_in[1];
    const float* bias = (const float*)d_in[2];
    float* out = (float*)d_out;

    const int N = in_sizes[2];
    const int K = in_sizes[1] / N;
    const int M = in_sizes[0] / K;

    uint16_t* xq = (uint16_t*)d_ws;
    uint16_t* wq = xq + (size_t)M * K;

    const int xquads = (M * K) / 4;
    const int totquads = xquads + (N * K) / 4;
    const int half = totquads / 2;
    quant_fp4_fused<<<(half + 255) / 256, 256, 0, stream>>>(x, w, xq, xquads, totquads);

    const int nwg = (M >> 8) * (N >> 8);
    gemm_w4a4<<<nwg, THREADS, 0, stream>>>(xq, wq, bias, out, M, N, K);
}